// Round 1
// baseline (59261.719 us; speedup 1.0000x reference)
//
#include <hip/hip_runtime.h>
#include <math.h>

#define NBLK   64
#define BS     256
#define NSTATE 17
#define NH     256
#define NX     273      // NH + NSTATE
#define WID    1024
#define NT     64
#define NSUB   8
#define ROWS_H (WID/NBLK)   // 16 rows per block for 1024-wide layers
#define ROWS_L (NH/NBLK)    // 4 rows per block for the 256-wide output layer

__device__ __forceinline__ float softplus_f(float v) {
    // matches jax.nn.softplus = max(x,0) + log1p(exp(-|x|))
    return fmaxf(v, 0.f) + log1pf(expf(-fabsf(v)));
}

// Sense-reversing grid barrier. Release-only on arrive (writes back dirty L2
// lines: the z/dh slices). NO acquire cache-inv anywhere: all cross-block
// reads go through __hip_atomic_load(RELAXED, AGENT) which bypasses L1/L2,
// so the weight working set stays L2-hot across all 10k barriers.
__device__ __forceinline__ void grid_barrier(unsigned* cnt, unsigned* gen) {
    __syncthreads();   // drains vmcnt: all block stores complete before arrive
    if (threadIdx.x == 0) {
        unsigned g0 = __hip_atomic_load(gen, __ATOMIC_RELAXED, __HIP_MEMORY_SCOPE_AGENT);
        unsigned my = __hip_atomic_fetch_add(cnt, 1u, __ATOMIC_RELEASE, __HIP_MEMORY_SCOPE_AGENT);
        if (my == NBLK - 1u) {
            __hip_atomic_store(cnt, 0u, __ATOMIC_RELAXED, __HIP_MEMORY_SCOPE_AGENT);
            __hip_atomic_store(gen, g0 + 1u, __ATOMIC_RELEASE, __HIP_MEMORY_SCOPE_AGENT);
        } else {
            while (__hip_atomic_load(gen, __ATOMIC_RELAXED, __HIP_MEMORY_SCOPE_AGENT) == g0) {
                __builtin_amdgcn_s_sleep(1);
            }
        }
    }
    __syncthreads();
}

__device__ __forceinline__ float coh_load(const float* p) {
    return __hip_atomic_load(p, __ATOMIC_RELAXED, __HIP_MEMORY_SCOPE_AGENT);
}

extern "C" __global__ __launch_bounds__(BS, 1) void ode_kernel(
    const float* __restrict__ ts,   const float* __restrict__ W0,
    const float* __restrict__ b0,   const float* __restrict__ Wh,
    const float* __restrict__ bh,   const float* __restrict__ Wl,
    const float* __restrict__ bl,   const float* __restrict__ betaW,
    const float* __restrict__ betab,const float* __restrict__ hvec,
    const float* __restrict__ scale,const float* __restrict__ y0log,
    float* __restrict__ out, float* zA, float* zB, float* dhb, unsigned* bar)
{
    const int t   = threadIdx.x;
    const int blk = blockIdx.x;

    __shared__ float y_s[NX];    // current y  [state(17), h(256)]
    __shared__ float yn_s[NX];   // RK4 accumulator
    __shared__ float x_s[NX];    // stage input  y + a*dt*k_prev
    __shared__ float xm[NX];     // MLP input: [h, state]
    __shared__ float k_s[NX];    // current k:  [dstate, dh]
    __shared__ float z_s[WID];   // staged layer-input vector
    __shared__ float red[4];
    __shared__ float dt_sh;

    unsigned* cnt = &bar[0];
    unsigned* gen = &bar[32];

    const float scale0 = scale[0];
    const float betab0 = betab[0];

    // ---- y0 = [softmax(y0_log), hvec] ----
    if (t < NSTATE) {
        float m = -1e30f;
        for (int j = 0; j < NSTATE; j++) m = fmaxf(m, y0log[j]);
        float ssum = 0.f;
        for (int j = 0; j < NSTATE; j++) ssum += expf(y0log[j] - m);
        y_s[t] = expf(y0log[t] - m) / ssum;
    }
    y_s[NSTATE + t] = hvec[t];
    __syncthreads();

    if (blk == 0) {
        if (t < NSTATE) out[t] = y_s[t];
        out[NT * NSTATE + t] = y_s[NSTATE + t];
    }

    const float c_xi = 13.f / 12.f, c_mu = 0.041f / 12.f, c_sig = 91.f / 12.f,
                c_nu = 36.f / 12.f, c_gam = 1.8f / 12.f;

    for (int iv = 0; iv < NT - 1; iv++) {
        if (t == 0) dt_sh = (ts[iv + 1] - ts[iv]) * (1.f / NSUB);
        __syncthreads();
        const float dt = dt_sh;

        for (int sub = 0; sub < NSUB; sub++) {
            for (int i = t; i < NX; i += BS) yn_s[i] = y_s[i];

            for (int s = 0; s < 4; s++) {
                const float a = (s == 0) ? 0.f : ((s == 3) ? 1.f : 0.5f);
                const float w = ((s == 0) || (s == 3)) ? dt * (1.f / 6.f) : dt * (1.f / 3.f);

                // ---- stage input x = y + a*dt*k_prev ----
                if (s == 0) { for (int i = t; i < NX; i += BS) x_s[i] = y_s[i]; }
                else        { for (int i = t; i < NX; i += BS) x_s[i] = y_s[i] + a * dt * k_s[i]; }
                __syncthreads();

                // ---- MLP input reorder + beta head partial ----
                xm[t] = x_s[NSTATE + t];
                if (t < NSTATE) xm[NH + t] = x_s[t];
                float p = betaW[t] * x_s[NSTATE + t];
                #pragma unroll
                for (int m = 1; m < 64; m <<= 1) p += __shfl_xor(p, m, 64);
                if ((t & 63) == 0) red[t >> 6] = p;
                __syncthreads();

                // ---- dstate (redundant per block, thread 0) ----
                if (t == 0) {
                    float sd  = red[0] + red[1] + red[2] + red[3] + betab0;
                    float bb1 = 8.f / (1.f + expf(-sd)) + 25.f;
                    float bb2 = 0.5f * bb1, bb3 = 0.35f * bb1, bb4 = 0.25f * bb1;
                    float M  = x_s[0],  S1 = x_s[1],  E1 = x_s[2],  E2 = x_s[3];
                    float E3 = x_s[4],  E4 = x_s[5],  I1 = x_s[6],  I2 = x_s[7];
                    float I3 = x_s[8],  I4 = x_s[9],  R1 = x_s[10], R2 = x_s[11];
                    float R3 = x_s[12], R4 = x_s[13], S2 = x_s[14], S3 = x_s[15];
                    float S4 = x_s[16];
                    float I = I1 + I2 + I3 + I4, R = R1 + R2 + R3 + R4;
                    k_s[0]  = R * c_mu - (c_xi + c_mu) * M;
                    k_s[1]  = c_mu * (1.f - R) + c_xi * M - c_mu * S1 - bb1 * I * S1;
                    k_s[2]  = bb1 * I * S1 - (c_mu + c_sig) * E1;
                    k_s[3]  = bb2 * I * S2 - (c_mu + c_sig) * E2;
                    k_s[4]  = bb3 * I * S3 - (c_mu + c_sig) * E3;
                    k_s[5]  = bb4 * I * S4 - (c_mu + c_sig) * E4;
                    k_s[6]  = c_sig * E1 - (c_nu + c_mu) * I1;
                    k_s[7]  = c_sig * E2 - (c_nu + c_mu) * I2;
                    k_s[8]  = c_sig * E3 - (c_nu + c_mu) * I3;
                    k_s[9]  = c_sig * E4 - (c_nu + c_mu) * I4;
                    k_s[10] = c_nu * I1 - (c_mu + c_gam) * R1;
                    k_s[11] = c_nu * I2 - (c_mu + c_gam) * R2;
                    k_s[12] = c_nu * I3 - (c_mu + c_gam) * R3;
                    k_s[13] = c_nu * I4 - (c_mu + c_gam) * R4;
                    k_s[14] = c_gam * R1 - c_mu * S2 - bb2 * I * S2;
                    k_s[15] = c_gam * R2 - c_mu * S3 - bb3 * I * S3;
                    k_s[16] = c_gam * (R3 + R4) - c_mu * S4 - bb4 * I * S4;
                }
                __syncthreads();

                // ---- L0: 1024x273, 16 rows/block, 16 lanes/row ----
                {
                    int row = t >> 4, lane = t & 15;
                    int grow = blk * ROWS_H + row;
                    const float* wr = W0 + (size_t)grow * NX;
                    float acc = 0.f;
                    for (int c = lane; c < NX; c += 16) acc += wr[c] * xm[c];
                    #pragma unroll
                    for (int m = 1; m < 16; m <<= 1) acc += __shfl_xor(acc, m, 16);
                    if (lane == 0) zA[grow] = softplus_f(acc + b0[grow]);
                }
                grid_barrier(cnt, gen);

                // ---- hidden layers 1..3: 1024x1024 ----
                float* zp[2] = { zA, zB };
                int cur = 0;
                for (int l = 0; l < 3; l++) {
                    const float* zin = zp[cur];
                    float* zout = zp[cur ^ 1];
                    for (int i = t; i < WID; i += BS) z_s[i] = coh_load(zin + i);
                    __syncthreads();
                    int row = t >> 4, lane = t & 15;
                    int grow = blk * ROWS_H + row;
                    const float* wr = Wh + (size_t)l * WID * WID + (size_t)grow * WID;
                    float acc = 0.f;
                    #pragma unroll
                    for (int i = 0; i < 16; i++) {
                        int c = lane * 4 + i * 64;
                        float4 wv = *(const float4*)(wr + c);
                        float4 zv = *(const float4*)(z_s + c);
                        acc += wv.x * zv.x + wv.y * zv.y + wv.z * zv.z + wv.w * zv.w;
                    }
                    #pragma unroll
                    for (int m = 1; m < 16; m <<= 1) acc += __shfl_xor(acc, m, 16);
                    if (lane == 0) zout[grow] = softplus_f(acc + bh[l * WID + grow]);
                    grid_barrier(cnt, gen);
                    cur ^= 1;
                }

                // ---- Wl: 256x1024, 4 rows/block, 64 lanes/row; tanh epilogue ----
                {
                    const float* zin = zp[cur];   // L3 output
                    for (int i = t; i < WID; i += BS) z_s[i] = coh_load(zin + i);
                    __syncthreads();
                    int row = t >> 6, lane = t & 63;
                    int grow = blk * ROWS_L + row;
                    const float* wr = Wl + (size_t)grow * WID;
                    float acc = 0.f;
                    #pragma unroll
                    for (int i = 0; i < 4; i++) {
                        int c = lane * 4 + i * 256;
                        float4 wv = *(const float4*)(wr + c);
                        float4 zv = *(const float4*)(z_s + c);
                        acc += wv.x * zv.x + wv.y * zv.y + wv.z * zv.z + wv.w * zv.w;
                    }
                    #pragma unroll
                    for (int m = 1; m < 64; m <<= 1) acc += __shfl_xor(acc, m, 64);
                    if (lane == 0) dhb[grow] = scale0 * tanhf(0.01f * (acc + bl[grow]));
                }
                grid_barrier(cnt, gen);

                // ---- gather dh, accumulate RK4 ----
                k_s[NSTATE + t] = coh_load(dhb + t);
                __syncthreads();
                for (int i = t; i < NX; i += BS) yn_s[i] += w * k_s[i];
                // no sync needed: same-thread index mapping for yn_s
            } // stages

            for (int i = t; i < NX; i += BS) y_s[i] = yn_s[i];
            __syncthreads();
        } // substeps

        if (blk == 0) {
            if (t < NSTATE) out[(iv + 1) * NSTATE + t] = y_s[t];
            out[NT * NSTATE + (iv + 1) * NH + t] = y_s[NSTATE + t];
        }
    } // intervals
}

extern "C" void kernel_launch(void* const* d_in, const int* in_sizes, int n_in,
                              void* d_out, int out_size, void* d_ws, size_t ws_size,
                              hipStream_t stream) {
    const float* ts    = (const float*)d_in[0];
    const float* W0    = (const float*)d_in[1];
    const float* b0    = (const float*)d_in[2];
    const float* Wh    = (const float*)d_in[3];
    const float* bh    = (const float*)d_in[4];
    const float* Wl    = (const float*)d_in[5];
    const float* bl    = (const float*)d_in[6];
    const float* betaW = (const float*)d_in[7];
    const float* betab = (const float*)d_in[8];
    const float* hvec  = (const float*)d_in[9];
    const float* scale = (const float*)d_in[10];
    const float* y0log = (const float*)d_in[11];
    float* out = (float*)d_out;

    unsigned* bar = (unsigned*)d_ws;                  // cnt @ +0, gen @ +128
    float* zA  = (float*)((char*)d_ws + 256);
    float* zB  = zA + WID;
    float* dhb = zB + WID;

    hipMemsetAsync(d_ws, 0, 256, stream);             // zero the barrier state
    hipLaunchKernelGGL(ode_kernel, dim3(NBLK), dim3(BS), 0, stream,
                       ts, W0, b0, Wh, bh, Wl, bl, betaW, betab, hvec, scale,
                       y0log, out, zA, zB, dhb, bar);
}

// Round 2
// 42202.832 us; speedup vs baseline: 1.4042x; 1.4042x over previous
//
#include <hip/hip_runtime.h>
#include <math.h>

#define NBLK   64
#define BS     256
#define NSTATE 17
#define NH     256
#define NX     273      // NH + NSTATE
#define WID    1024
#define NT     64
#define NSUB   8
#define ROWS_H (WID/NBLK)   // 16 rows per block for 1024-wide layers
#define ROWS_L (NH/NBLK)    // 4 rows per block for the 256-wide output layer

__device__ __forceinline__ float softplus_f(float v) {
    return fmaxf(v, 0.f) + log1pf(expf(-fabsf(v)));
}

// Cross-block data: write-through to the coherence point (IF$), never dirty
// in a producer's L2, so no wbl2 walks are ever needed for the payload.
__device__ __forceinline__ void st_coh(float* p, float v) {
    __hip_atomic_store(p, v, __ATOMIC_RELAXED, __HIP_MEMORY_SCOPE_AGENT);
}
__device__ __forceinline__ float ld_coh(const float* p) {
    return __hip_atomic_load(p, __ATOMIC_RELAXED, __HIP_MEMORY_SCOPE_AGENT);
}

// One-way epoch signaling: each block owns flag[blk] (128B apart), stores the
// monotonically-increasing round number R after its slice stores have drained
// (__syncthreads emits s_waitcnt vmcnt(0) before s_barrier). RELEASE on the
// flag store gives the hw ordering guarantee; since nothing cross-block is
// L2-dirty, its wbl2 is ~free.
__device__ __forceinline__ void publish(unsigned* flags, int blk, unsigned R) {
    __syncthreads();
    if (threadIdx.x == 0)
        __hip_atomic_store(&flags[blk * 32], R, __ATOMIC_RELEASE, __HIP_MEMORY_SCOPE_AGENT);
}

// Wave 0 polls all 64 flags (one lane each); exit when everyone reached R.
__device__ __forceinline__ void wait_flags(const unsigned* flags, unsigned R) {
    if (threadIdx.x < 64) {
        unsigned v;
        do {
            v = __hip_atomic_load(&flags[threadIdx.x * 32],
                                  __ATOMIC_RELAXED, __HIP_MEMORY_SCOPE_AGENT);
        } while (__ballot(v >= R) != ~0ull);
    }
    __syncthreads();
    __atomic_signal_fence(__ATOMIC_SEQ_CST);  // keep consume loads below the poll
}

extern "C" __global__ __launch_bounds__(BS, 1) void ode_kernel(
    const float* __restrict__ ts,   const float* __restrict__ W0,
    const float* __restrict__ b0,   const float* __restrict__ Wh,
    const float* __restrict__ bh,   const float* __restrict__ Wl,
    const float* __restrict__ bl,   const float* __restrict__ betaW,
    const float* __restrict__ betab,const float* __restrict__ hvec,
    const float* __restrict__ scale,const float* __restrict__ y0log,
    float* __restrict__ out, float* zA, float* zB, float* dhb, unsigned* flags)
{
    const int t   = threadIdx.x;
    const int blk = blockIdx.x;

    __shared__ float y_s[NX];
    __shared__ float yn_s[NX];
    __shared__ float x_s[NX];
    __shared__ float xm[NX];
    __shared__ float k_s[NX];
    __shared__ float z_s[WID];
    __shared__ float red[4];
    __shared__ float dt_sh;

    const float scale0 = scale[0];
    const float betab0 = betab[0];
    unsigned R = 0;   // global communication round; identical sequence on all blocks

    // ---- y0 = [softmax(y0_log), hvec] ----
    if (t < NSTATE) {
        float m = -1e30f;
        for (int j = 0; j < NSTATE; j++) m = fmaxf(m, y0log[j]);
        float ssum = 0.f;
        for (int j = 0; j < NSTATE; j++) ssum += expf(y0log[j] - m);
        y_s[t] = expf(y0log[t] - m) / ssum;
    }
    y_s[NSTATE + t] = hvec[t];
    __syncthreads();

    if (blk == 0) {
        if (t < NSTATE) out[t] = y_s[t];
        out[NT * NSTATE + t] = y_s[NSTATE + t];
    }

    const float c_xi = 13.f / 12.f, c_mu = 0.041f / 12.f, c_sig = 91.f / 12.f,
                c_nu = 36.f / 12.f, c_gam = 1.8f / 12.f;

    const int rowH = t >> 4, laneH = t & 15;
    const int growH = blk * ROWS_H + rowH;
    const int rowL = t >> 6, laneL = t & 63;
    const int growL = blk * ROWS_L + rowL;

    for (int iv = 0; iv < NT - 1; iv++) {
        if (t == 0) dt_sh = (ts[iv + 1] - ts[iv]) * (1.f / NSUB);
        __syncthreads();
        const float dt = dt_sh;

        for (int sub = 0; sub < NSUB; sub++) {
            for (int i = t; i < NX; i += BS) yn_s[i] = y_s[i];

            for (int s = 0; s < 4; s++) {
                const float a = (s == 0) ? 0.f : ((s == 3) ? 1.f : 0.5f);
                const float w = ((s == 0) || (s == 3)) ? dt * (1.f / 6.f) : dt * (1.f / 3.f);

                // ---- stage input x = y + a*dt*k_prev (k_s valid from prev stage) ----
                if (s == 0) { for (int i = t; i < NX; i += BS) x_s[i] = y_s[i]; }
                else        { for (int i = t; i < NX; i += BS) x_s[i] = y_s[i] + a * dt * k_s[i]; }
                __syncthreads();

                // ---- MLP input reorder + beta head partial ----
                xm[t] = x_s[NSTATE + t];
                if (t < NSTATE) xm[NH + t] = x_s[t];
                float p = betaW[t] * x_s[NSTATE + t];
                #pragma unroll
                for (int m = 1; m < 64; m <<= 1) p += __shfl_xor(p, m, 64);
                if ((t & 63) == 0) red[t >> 6] = p;
                __syncthreads();

                // ---- dstate (redundant per block, thread 0) ----
                if (t == 0) {
                    float sd  = red[0] + red[1] + red[2] + red[3] + betab0;
                    float bb1 = 8.f / (1.f + expf(-sd)) + 25.f;
                    float bb2 = 0.5f * bb1, bb3 = 0.35f * bb1, bb4 = 0.25f * bb1;
                    float M  = x_s[0],  S1 = x_s[1],  E1 = x_s[2],  E2 = x_s[3];
                    float E3 = x_s[4],  E4 = x_s[5],  I1 = x_s[6],  I2 = x_s[7];
                    float I3 = x_s[8],  I4 = x_s[9],  R1 = x_s[10], R2 = x_s[11];
                    float R3 = x_s[12], R4 = x_s[13], S2 = x_s[14], S3 = x_s[15];
                    float S4 = x_s[16];
                    float I = I1 + I2 + I3 + I4, Rs = R1 + R2 + R3 + R4;
                    k_s[0]  = Rs * c_mu - (c_xi + c_mu) * M;
                    k_s[1]  = c_mu * (1.f - Rs) + c_xi * M - c_mu * S1 - bb1 * I * S1;
                    k_s[2]  = bb1 * I * S1 - (c_mu + c_sig) * E1;
                    k_s[3]  = bb2 * I * S2 - (c_mu + c_sig) * E2;
                    k_s[4]  = bb3 * I * S3 - (c_mu + c_sig) * E3;
                    k_s[5]  = bb4 * I * S4 - (c_mu + c_sig) * E4;
                    k_s[6]  = c_sig * E1 - (c_nu + c_mu) * I1;
                    k_s[7]  = c_sig * E2 - (c_nu + c_mu) * I2;
                    k_s[8]  = c_sig * E3 - (c_nu + c_mu) * I3;
                    k_s[9]  = c_sig * E4 - (c_nu + c_mu) * I4;
                    k_s[10] = c_nu * I1 - (c_mu + c_gam) * R1;
                    k_s[11] = c_nu * I2 - (c_mu + c_gam) * R2;
                    k_s[12] = c_nu * I3 - (c_mu + c_gam) * R3;
                    k_s[13] = c_nu * I4 - (c_mu + c_gam) * R4;
                    k_s[14] = c_gam * R1 - c_mu * S2 - bb2 * I * S2;
                    k_s[15] = c_gam * R2 - c_mu * S3 - bb3 * I * S3;
                    k_s[16] = c_gam * (R3 + R4) - c_mu * S4 - bb4 * I * S4;
                }
                __syncthreads();

                // ---- L0: 1024x273, 16 rows/block, 16 lanes/row (input is local) ----
                {
                    const float* wr = W0 + (size_t)growH * NX;
                    float acc = 0.f;
                    for (int c = laneH; c < NX; c += 16) acc += wr[c] * xm[c];
                    #pragma unroll
                    for (int m = 1; m < 16; m <<= 1) acc += __shfl_xor(acc, m, 16);
                    if (laneH == 0) st_coh(&zA[growH], softplus_f(acc + b0[growH]));
                }
                ++R; publish(flags, blk, R);

                // ---- hidden layers 1..3: 1024x1024, weights prefetched during poll ----
                float* zp[2] = { zA, zB };
                int cur = 0;
                for (int l = 0; l < 3; l++) {
                    const float* zin = zp[cur];
                    float* zout = zp[cur ^ 1];
                    const float* wr = Wh + (size_t)l * WID * WID + (size_t)growH * WID;
                    float4 wv[16];
                    #pragma unroll
                    for (int i = 0; i < 16; i++)
                        wv[i] = *(const float4*)(wr + (laneH * 4 + i * 64));

                    wait_flags(flags, R);
                    for (int i = t; i < WID; i += BS) z_s[i] = ld_coh(zin + i);
                    __syncthreads();

                    float acc = 0.f;
                    #pragma unroll
                    for (int i = 0; i < 16; i++) {
                        float4 zv = *(const float4*)(z_s + (laneH * 4 + i * 64));
                        acc += wv[i].x * zv.x + wv[i].y * zv.y + wv[i].z * zv.z + wv[i].w * zv.w;
                    }
                    #pragma unroll
                    for (int m = 1; m < 16; m <<= 1) acc += __shfl_xor(acc, m, 16);
                    if (laneH == 0) st_coh(&zout[growH], softplus_f(acc + bh[l * WID + growH]));
                    ++R; publish(flags, blk, R);
                    cur ^= 1;
                }

                // ---- Wl: 256x1024, 4 rows/block, 64 lanes/row; tanh epilogue ----
                {
                    const float* zin = zp[cur];
                    const float* wr = Wl + (size_t)growL * WID;
                    float4 wv[4];
                    #pragma unroll
                    for (int i = 0; i < 4; i++)
                        wv[i] = *(const float4*)(wr + (laneL * 4 + i * 256));

                    wait_flags(flags, R);
                    for (int i = t; i < WID; i += BS) z_s[i] = ld_coh(zin + i);
                    __syncthreads();

                    float acc = 0.f;
                    #pragma unroll
                    for (int i = 0; i < 4; i++) {
                        float4 zv = *(const float4*)(z_s + (laneL * 4 + i * 256));
                        acc += wv[i].x * zv.x + wv[i].y * zv.y + wv[i].z * zv.z + wv[i].w * zv.w;
                    }
                    #pragma unroll
                    for (int m = 1; m < 64; m <<= 1) acc += __shfl_xor(acc, m, 64);
                    if (laneL == 0)
                        st_coh(&dhb[growL], scale0 * tanhf(0.01f * (acc + bl[growL])));
                }
                ++R; publish(flags, blk, R);

                // ---- gather dh, accumulate RK4 ----
                wait_flags(flags, R);
                k_s[NSTATE + t] = ld_coh(dhb + t);
                __syncthreads();
                for (int i = t; i < NX; i += BS) yn_s[i] += w * k_s[i];
            } // stages

            __syncthreads();
            for (int i = t; i < NX; i += BS) y_s[i] = yn_s[i];
            __syncthreads();
        } // substeps

        if (blk == 0) {
            if (t < NSTATE) out[(iv + 1) * NSTATE + t] = y_s[t];
            out[NT * NSTATE + (iv + 1) * NH + t] = y_s[NSTATE + t];
        }
    } // intervals
}

extern "C" void kernel_launch(void* const* d_in, const int* in_sizes, int n_in,
                              void* d_out, int out_size, void* d_ws, size_t ws_size,
                              hipStream_t stream) {
    const float* ts    = (const float*)d_in[0];
    const float* W0    = (const float*)d_in[1];
    const float* b0    = (const float*)d_in[2];
    const float* Wh    = (const float*)d_in[3];
    const float* bh    = (const float*)d_in[4];
    const float* Wl    = (const float*)d_in[5];
    const float* bl    = (const float*)d_in[6];
    const float* betaW = (const float*)d_in[7];
    const float* betab = (const float*)d_in[8];
    const float* hvec  = (const float*)d_in[9];
    const float* scale = (const float*)d_in[10];
    const float* y0log = (const float*)d_in[11];
    float* out = (float*)d_out;

    unsigned* flags = (unsigned*)d_ws;                 // 64 flags, 128B apart = 8KB
    float* zA  = (float*)((char*)d_ws + 8192);         // 4KB
    float* zB  = (float*)((char*)d_ws + 8192 + 4096);  // 4KB
    float* dhb = (float*)((char*)d_ws + 8192 + 8192);  // 1KB

    hipMemsetAsync(d_ws, 0, 8192, stream);             // zero epoch flags
    hipLaunchKernelGGL(ode_kernel, dim3(NBLK), dim3(BS), 0, stream,
                       ts, W0, b0, Wh, bh, Wl, bl, betaW, betab, hvec, scale,
                       y0log, out, zA, zB, dhb, flags);
}

// Round 3
// 34179.376 us; speedup vs baseline: 1.7338x; 1.2347x over previous
//
#include <hip/hip_runtime.h>
#include <math.h>

#define NBLK   64
#define BS     256
#define NSTATE 17
#define NH     256
#define NX     273      // NH + NSTATE
#define WID    1024
#define NT     64
#define NSUB   8
#define ROWS_H (WID/NBLK)   // 16 rows per block for 1024-wide layers
#define ROWS_L (NH/NBLK)    // 4 rows per block for the 256-wide output layer

typedef unsigned long long u64;

__device__ __forceinline__ float softplus_f(float v) {
    return fmaxf(v, 0.f) + log1pf(expf(-fabsf(v)));
}

// Tagged-word exchange: {round_tag:32 | fp32_bits:32} in one 64-bit word.
// RELAXED AGENT atomics: write-through to the coherence point, bypass L1/L2
// on load. No release fences anywhere -> no buffer_wbl2 L2 walks. The tag IS
// the synchronization: a consumer spins until the tag equals the expected
// round, and the value arrives in the same load.
__device__ __forceinline__ void st_tag(u64* p, float v, unsigned R) {
    u64 w = ((u64)R << 32) | (u64)__float_as_uint(v);
    __hip_atomic_store(p, w, __ATOMIC_RELAXED, __HIP_MEMORY_SCOPE_AGENT);
}
__device__ __forceinline__ u64 ld_tag(const u64* p) {
    return __hip_atomic_load(p, __ATOMIC_RELAXED, __HIP_MEMORY_SCOPE_AGENT);
}

// Poll a 1024-word tagged buffer into LDS. Thread t owns words
// {t, t+256, t+512, t+768} (wave-coalesced, 4 loads in flight).
__device__ __forceinline__ void poll_z(const u64* __restrict__ buf, unsigned R,
                                       float* __restrict__ z_s, int t) {
    float v[4];
    unsigned done = 0;
    while (done != 0xFu) {
        #pragma unroll
        for (int i = 0; i < 4; i++) {
            if (!(done & (1u << i))) {
                u64 w = ld_tag(buf + t + i * 256);
                if ((unsigned)(w >> 32) == R) {
                    v[i] = __uint_as_float((unsigned)w);
                    done |= 1u << i;
                }
            }
        }
    }
    #pragma unroll
    for (int i = 0; i < 4; i++) z_s[t + i * 256] = v[i];
    __syncthreads();
}

extern "C" __global__ __launch_bounds__(BS, 1) void ode_kernel(
    const float* __restrict__ ts,   const float* __restrict__ W0,
    const float* __restrict__ b0,   const float* __restrict__ Wh,
    const float* __restrict__ bh,   const float* __restrict__ Wl,
    const float* __restrict__ bl,   const float* __restrict__ betaW,
    const float* __restrict__ betab,const float* __restrict__ hvec,
    const float* __restrict__ scale,const float* __restrict__ y0log,
    float* __restrict__ out, u64* zA, u64* zB, u64* dhb)
{
    const int t   = threadIdx.x;
    const int blk = blockIdx.x;

    __shared__ float y_s[NX];
    __shared__ float yn_s[NX];
    __shared__ float x_s[NX];
    __shared__ float xm[NX];
    __shared__ float k_s[NX];
    __shared__ float z_s[WID];
    __shared__ float red[4];
    __shared__ float dt_sh;

    const float scale0 = scale[0];
    const float betab0 = betab[0];
    unsigned R = 0;   // global exchange round; identical sequence on all blocks

    // ---- y0 = [softmax(y0_log), hvec] ----
    if (t < NSTATE) {
        float m = -1e30f;
        for (int j = 0; j < NSTATE; j++) m = fmaxf(m, y0log[j]);
        float ssum = 0.f;
        for (int j = 0; j < NSTATE; j++) ssum += expf(y0log[j] - m);
        y_s[t] = expf(y0log[t] - m) / ssum;
    }
    y_s[NSTATE + t] = hvec[t];
    __syncthreads();

    if (blk == 0) {
        if (t < NSTATE) out[t] = y_s[t];
        out[NT * NSTATE + t] = y_s[NSTATE + t];
    }

    const float c_xi = 13.f / 12.f, c_mu = 0.041f / 12.f, c_sig = 91.f / 12.f,
                c_nu = 36.f / 12.f, c_gam = 1.8f / 12.f;

    const int rowH = t >> 4, laneH = t & 15;
    const int growH = blk * ROWS_H + rowH;
    const int rowL = t >> 6, laneL = t & 63;
    const int growL = blk * ROWS_L + rowL;

    for (int iv = 0; iv < NT - 1; iv++) {
        if (t == 0) dt_sh = (ts[iv + 1] - ts[iv]) * (1.f / NSUB);
        __syncthreads();
        const float dt = dt_sh;

        for (int sub = 0; sub < NSUB; sub++) {
            for (int i = t; i < NX; i += BS) yn_s[i] = y_s[i];

            for (int s = 0; s < 4; s++) {
                const float a = (s == 0) ? 0.f : ((s == 3) ? 1.f : 0.5f);
                const float w = ((s == 0) || (s == 3)) ? dt * (1.f / 6.f) : dt * (1.f / 3.f);

                // ---- stage input x = y + a*dt*k_prev ----
                if (s == 0) { for (int i = t; i < NX; i += BS) x_s[i] = y_s[i]; }
                else        { for (int i = t; i < NX; i += BS) x_s[i] = y_s[i] + a * dt * k_s[i]; }
                __syncthreads();

                // ---- MLP input reorder + beta head partial ----
                xm[t] = x_s[NSTATE + t];
                if (t < NSTATE) xm[NH + t] = x_s[t];
                float p = betaW[t] * x_s[NSTATE + t];
                #pragma unroll
                for (int m = 1; m < 64; m <<= 1) p += __shfl_xor(p, m, 64);
                if ((t & 63) == 0) red[t >> 6] = p;
                __syncthreads();

                // ---- dstate (redundant per block, thread 0) ----
                if (t == 0) {
                    float sd  = red[0] + red[1] + red[2] + red[3] + betab0;
                    float bb1 = 8.f / (1.f + expf(-sd)) + 25.f;
                    float bb2 = 0.5f * bb1, bb3 = 0.35f * bb1, bb4 = 0.25f * bb1;
                    float M  = x_s[0],  S1 = x_s[1],  E1 = x_s[2],  E2 = x_s[3];
                    float E3 = x_s[4],  E4 = x_s[5],  I1 = x_s[6],  I2 = x_s[7];
                    float I3 = x_s[8],  I4 = x_s[9],  R1 = x_s[10], R2 = x_s[11];
                    float R3 = x_s[12], R4 = x_s[13], S2 = x_s[14], S3 = x_s[15];
                    float S4 = x_s[16];
                    float I = I1 + I2 + I3 + I4, Rs = R1 + R2 + R3 + R4;
                    k_s[0]  = Rs * c_mu - (c_xi + c_mu) * M;
                    k_s[1]  = c_mu * (1.f - Rs) + c_xi * M - c_mu * S1 - bb1 * I * S1;
                    k_s[2]  = bb1 * I * S1 - (c_mu + c_sig) * E1;
                    k_s[3]  = bb2 * I * S2 - (c_mu + c_sig) * E2;
                    k_s[4]  = bb3 * I * S3 - (c_mu + c_sig) * E3;
                    k_s[5]  = bb4 * I * S4 - (c_mu + c_sig) * E4;
                    k_s[6]  = c_sig * E1 - (c_nu + c_mu) * I1;
                    k_s[7]  = c_sig * E2 - (c_nu + c_mu) * I2;
                    k_s[8]  = c_sig * E3 - (c_nu + c_mu) * I3;
                    k_s[9]  = c_sig * E4 - (c_nu + c_mu) * I4;
                    k_s[10] = c_nu * I1 - (c_mu + c_gam) * R1;
                    k_s[11] = c_nu * I2 - (c_mu + c_gam) * R2;
                    k_s[12] = c_nu * I3 - (c_mu + c_gam) * R3;
                    k_s[13] = c_nu * I4 - (c_mu + c_gam) * R4;
                    k_s[14] = c_gam * R1 - c_mu * S2 - bb2 * I * S2;
                    k_s[15] = c_gam * R2 - c_mu * S3 - bb3 * I * S3;
                    k_s[16] = c_gam * (R3 + R4) - c_mu * S4 - bb4 * I * S4;
                }
                __syncthreads();

                // ---- L0: 1024x273, 16 rows/block, 16 lanes/row (input local) ----
                {
                    const float* wr = W0 + (size_t)growH * NX;
                    float acc = 0.f;
                    for (int c = laneH; c < NX; c += 16) acc += wr[c] * xm[c];
                    #pragma unroll
                    for (int m = 1; m < 16; m <<= 1) acc += __shfl_xor(acc, m, 16);
                    ++R;
                    if (laneH == 0) st_tag(&zA[growH], softplus_f(acc + b0[growH]), R);
                }

                // ---- hidden layers 1..3: 1024x1024; weights prefetch before poll ----
                u64* zp[2] = { zA, zB };
                int cur = 0;
                for (int l = 0; l < 3; l++) {
                    const u64* zin = zp[cur];
                    u64* zout = zp[cur ^ 1];
                    const float* wr = Wh + (size_t)l * WID * WID + (size_t)growH * WID;
                    float4 wv[16];
                    #pragma unroll
                    for (int i = 0; i < 16; i++)
                        wv[i] = *(const float4*)(wr + (laneH * 4 + i * 64));

                    poll_z(zin, R, z_s, t);

                    float acc = 0.f;
                    #pragma unroll
                    for (int i = 0; i < 16; i++) {
                        float4 zv = *(const float4*)(z_s + (laneH * 4 + i * 64));
                        acc += wv[i].x * zv.x + wv[i].y * zv.y + wv[i].z * zv.z + wv[i].w * zv.w;
                    }
                    #pragma unroll
                    for (int m = 1; m < 16; m <<= 1) acc += __shfl_xor(acc, m, 16);
                    ++R;
                    if (laneH == 0)
                        st_tag(&zout[growH], softplus_f(acc + bh[l * WID + growH]), R);
                    cur ^= 1;
                }

                // ---- Wl: 256x1024, 4 rows/block; tanh epilogue ----
                {
                    const u64* zin = zp[cur];   // h3 output
                    const float* wr = Wl + (size_t)growL * WID;
                    float4 wv[4];
                    #pragma unroll
                    for (int i = 0; i < 4; i++)
                        wv[i] = *(const float4*)(wr + (laneL * 4 + i * 256));

                    poll_z(zin, R, z_s, t);

                    float acc = 0.f;
                    #pragma unroll
                    for (int i = 0; i < 4; i++) {
                        float4 zv = *(const float4*)(z_s + (laneL * 4 + i * 256));
                        acc += wv[i].x * zv.x + wv[i].y * zv.y + wv[i].z * zv.z + wv[i].w * zv.w;
                    }
                    #pragma unroll
                    for (int m = 1; m < 64; m <<= 1) acc += __shfl_xor(acc, m, 64);
                    ++R;
                    if (laneL == 0)
                        st_tag(&dhb[growL], scale0 * tanhf(0.01f * (acc + bl[growL])), R);
                }

                // ---- gather dh (tagged poll, one word per thread) ----
                {
                    u64 w;
                    do { w = ld_tag(dhb + t); } while ((unsigned)(w >> 32) != R);
                    k_s[NSTATE + t] = __uint_as_float((unsigned)w);
                }
                __syncthreads();
                for (int i = t; i < NX; i += BS) yn_s[i] += w * k_s[i];
            } // stages

            __syncthreads();
            for (int i = t; i < NX; i += BS) y_s[i] = yn_s[i];
            __syncthreads();
        } // substeps

        if (blk == 0) {
            if (t < NSTATE) out[(iv + 1) * NSTATE + t] = y_s[t];
            out[NT * NSTATE + (iv + 1) * NH + t] = y_s[NSTATE + t];
        }
    } // intervals
}

extern "C" void kernel_launch(void* const* d_in, const int* in_sizes, int n_in,
                              void* d_out, int out_size, void* d_ws, size_t ws_size,
                              hipStream_t stream) {
    const float* ts    = (const float*)d_in[0];
    const float* W0    = (const float*)d_in[1];
    const float* b0    = (const float*)d_in[2];
    const float* Wh    = (const float*)d_in[3];
    const float* bh    = (const float*)d_in[4];
    const float* Wl    = (const float*)d_in[5];
    const float* bl    = (const float*)d_in[6];
    const float* betaW = (const float*)d_in[7];
    const float* betab = (const float*)d_in[8];
    const float* hvec  = (const float*)d_in[9];
    const float* scale = (const float*)d_in[10];
    const float* y0log = (const float*)d_in[11];
    float* out = (float*)d_out;

    u64* zA  = (u64*)d_ws;                          // 1024*8 = 8 KB
    u64* zB  = (u64*)((char*)d_ws + 8192);          // 8 KB
    u64* dhb = (u64*)((char*)d_ws + 16384);         // 2 KB

    // zero all tags (re-poisoned to 0xAA before every launch; tag 0 != any R>=1)
    hipMemsetAsync(d_ws, 0, 18432, stream);
    hipLaunchKernelGGL(ode_kernel, dim3(NBLK), dim3(BS), 0, stream,
                       ts, W0, b0, Wh, bh, Wl, bl, betaW, betab, hvec, scale,
                       y0log, out, zA, zB, dhb);
}